// Round 1
// 317.724 us; speedup vs baseline: 1.0043x; 1.0043x over previous
//
#include <hip/hip_runtime.h>

#define N_NODES 50000
#define N_EDGES 800000
#define FEATS   128
#define HID     32
#define HEADS   4
#define D1      128      // HEADS*HID
#define NGRAPH  64
#define SCAN_NB ((N_NODES + 1023) / 1024)   // 49

__device__ __forceinline__ float lrelu_(float v) { return v > 0.f ? v : 0.2f * v; }
__device__ __forceinline__ float elu_(float v)   { return v > 0.f ? v : __expf(v) - 1.f; }

// ---------- CSR build ----------
__global__ __launch_bounds__(256) void k_hist(const int* __restrict__ ei, int* __restrict__ deg)
{
    int e = blockIdx.x * 256 + threadIdx.x;
    if (e < N_EDGES) atomicAdd(&deg[ei[N_EDGES + e]], 1);
}

// phase A: per-block exclusive scan + block totals
__global__ __launch_bounds__(1024) void k_scan_local(
    const int* __restrict__ deg, int* __restrict__ rs, int* __restrict__ btot)
{
    __shared__ int sm[1024];
    int idx = blockIdx.x * 1024 + threadIdx.x;
    int v = (idx < N_NODES) ? deg[idx] : 0;
    sm[threadIdx.x] = v;
    __syncthreads();
    for (int off = 1; off < 1024; off <<= 1) {
        int t = (threadIdx.x >= off) ? sm[threadIdx.x - off] : 0;
        __syncthreads();
        sm[threadIdx.x] += t;
        __syncthreads();
    }
    if (idx < N_NODES) rs[idx] = sm[threadIdx.x] - v;   // exclusive
    if (threadIdx.x == 1023) btot[blockIdx.x] = sm[1023];
}

// phase B: single-wave shuffle scan of the 49 block totals -> exclusive offsets
__global__ __launch_bounds__(64) void k_scan_btot(
    const int* __restrict__ btot, int* __restrict__ boff)
{
    int t = threadIdx.x;
    int own = (t < SCAN_NB) ? btot[t] : 0;
    int v = own;
    for (int off = 1; off < 64; off <<= 1) {
        int u = __shfl_up(v, off);
        if (t >= off) v += u;
    }
    if (t < SCAN_NB) boff[t] = v - own;   // exclusive
}

// phase C: add block offsets; rs[N_NODES] = N_EDGES
__global__ __launch_bounds__(1024) void k_scan_add(
    int* __restrict__ rs, const int* __restrict__ boff)
{
    int idx = blockIdx.x * 1024 + threadIdx.x;
    if (idx < N_NODES) rs[idx] += boff[blockIdx.x];
    if (idx == N_NODES) rs[N_NODES] = N_EDGES;
}

__global__ __launch_bounds__(256) void k_scatter(const int* __restrict__ ei,
                                                const int* __restrict__ rs,
                                                int* __restrict__ cur,
                                                int* __restrict__ csr_src)
{
    int e = blockIdx.x * 256 + threadIdx.x;
    if (e >= N_EDGES) return;
    int d = ei[N_EDGES + e];
    int p = rs[d] + atomicAdd(&cur[d], 1);
    csr_src[p] = ei[e];
}

// graph boundaries from sorted batch
__global__ __launch_bounds__(256) void k_gbound(const int* __restrict__ batch, int* __restrict__ gstart)
{
    int i = blockIdx.x * 256 + threadIdx.x;
    if (i > N_NODES) return;
    int b    = (i < N_NODES) ? batch[i] : NGRAPH;
    int prev = (i == 0) ? -1 : batch[i - 1];
    for (int g = prev + 1; g <= b; ++g) gstart[g] = i;
}

// ---------- weight re-layout (one-time, tiny) ----------
__global__ __launch_bounds__(256) void k_wtrans1(
    const float* __restrict__ wl, const float* __restrict__ wr, float* __restrict__ wtg)
{
    int idx = blockIdx.x * 256 + threadIdx.x;   // 32768
    if (idx >= 32 * 256 * 4) return;
    int kk = idx & 3, j = (idx >> 2) & 255, k4 = idx >> 10;
    int k = k4 * 4 + kk;
    wtg[idx] = (j < 128) ? wl[j * FEATS + k] : wr[(j - 128) * FEATS + k];
}

__global__ __launch_bounds__(256) void k_wtrans2(
    const float* __restrict__ wl, const float* __restrict__ wr, float* __restrict__ wtg)
{
    int idx = blockIdx.x * 256 + threadIdx.x;   // 8192
    if (idx >= 32 * 64 * 4) return;
    int kk = idx & 3, j = (idx >> 2) & 63, k4 = idx >> 8;
    int k = k4 * 4 + kk;
    wtg[idx] = (j < 32) ? wl[j * D1 + k] : wr[(j - 32) * D1 + k];
}

// ---------- conv1 transform: 32 nodes/block, 8 nodes/thread, prefetched weights ----------
// per k4 step/thread: 4 global float4 (W, prefetched 1 iter ahead) + 8 broadcast LDS float4
// feeding 128 scalar FMAs. Reg budget ~acc32+xv32+w16+wn16 -> launch_bounds(256,2).
__global__ __launch_bounds__(256, 2) void k_transform1(
    const float* __restrict__ x, const float* __restrict__ wtg,
    const float* __restrict__ bl, const float* __restrict__ br,
    float* __restrict__ xl, float* __restrict__ xr)
{
    __shared__ float4 xs[32][32];   // [node][k4] : 16 KB
    int node0 = blockIdx.x * 32;
    for (int i = threadIdx.x; i < 1024; i += 256) {
        int r = i >> 5, k4 = i & 31;
        int n = node0 + r; if (n > N_NODES - 1) n = N_NODES - 1;   // tail clamp (pure fn -> benign dup)
        xs[r][k4] = *(const float4*)&x[(size_t)n * FEATS + k4 * 4];
    }
    __syncthreads();
    int jg = threadIdx.x & 63;
    int r0 = (threadIdx.x >> 6) * 8;
    const float4* wp = (const float4*)wtg;
    float acc[8][4];
#pragma unroll
    for (int r = 0; r < 8; ++r)
#pragma unroll
        for (int c = 0; c < 4; ++c) acc[r][c] = 0.f;

    float4 w[4];
#pragma unroll
    for (int c = 0; c < 4; ++c) w[c] = wp[jg + 64 * c];

#pragma unroll 2
    for (int k4 = 0; k4 < 32; ++k4) {
        int k4n = (k4 < 31) ? k4 + 1 : 31;
        float4 wn[4];
#pragma unroll
        for (int c = 0; c < 4; ++c) wn[c] = wp[k4n * 256 + jg + 64 * c];
        float4 xv[8];
#pragma unroll
        for (int r = 0; r < 8; ++r) xv[r] = xs[r0 + r][k4];
#pragma unroll
        for (int c = 0; c < 4; ++c)
#pragma unroll
            for (int r = 0; r < 8; ++r)
                acc[r][c] = fmaf(w[c].x, xv[r].x, fmaf(w[c].y, xv[r].y,
                            fmaf(w[c].z, xv[r].z, fmaf(w[c].w, xv[r].w, acc[r][c]))));
#pragma unroll
        for (int c = 0; c < 4; ++c) w[c] = wn[c];
    }
    float bl0 = bl[jg], bl1 = bl[jg + 64];
    float br0 = br[jg], br1 = br[jg + 64];
#pragma unroll
    for (int r = 0; r < 8; ++r) {
        int nn = node0 + r0 + r; if (nn > N_NODES - 1) nn = N_NODES - 1;
        size_t n = (size_t)nn;
        xl[n * D1 + jg]      = acc[r][0] + bl0;
        xl[n * D1 + jg + 64] = acc[r][1] + bl1;
        xr[n * D1 + jg]      = acc[r][2] + br0;
        xr[n * D1 + jg + 64] = acc[r][3] + br1;
    }
}

// ---------- conv2 transform: 64 nodes/block, 8 nodes/thread, 2 cols/thread ----------
__global__ __launch_bounds__(256, 2) void k_transform2(
    const float* __restrict__ hin, const float* __restrict__ wtg,
    const float* __restrict__ bl, const float* __restrict__ br,
    float* __restrict__ xl2, float* __restrict__ xr2)
{
    __shared__ float4 xs[64][32];   // 32 KB
    int node0 = blockIdx.x * 64;
    for (int i = threadIdx.x; i < 2048; i += 256) {
        int r = i >> 5, k4 = i & 31;
        int n = node0 + r; if (n > N_NODES - 1) n = N_NODES - 1;
        xs[r][k4] = *(const float4*)&hin[(size_t)n * D1 + k4 * 4];
    }
    __syncthreads();
    int j  = threadIdx.x & 31;        // output col (serves both L and R side)
    int r0 = (threadIdx.x >> 5) * 8;  // 8 groups x 8 nodes = 64
    const float4* wp = (const float4*)wtg;
    float accl[8], accr[8];
#pragma unroll
    for (int r = 0; r < 8; ++r) { accl[r] = 0.f; accr[r] = 0.f; }

    float4 wl_ = wp[j], wr_ = wp[j + 32];

#pragma unroll 2
    for (int k4 = 0; k4 < 32; ++k4) {
        int k4n = (k4 < 31) ? k4 + 1 : 31;
        float4 wln = wp[k4n * 64 + j];
        float4 wrn = wp[k4n * 64 + j + 32];
        float4 xv[8];
#pragma unroll
        for (int r = 0; r < 8; ++r) xv[r] = xs[r0 + r][k4];
#pragma unroll
        for (int r = 0; r < 8; ++r) {
            accl[r] = fmaf(wl_.x, xv[r].x, fmaf(wl_.y, xv[r].y,
                      fmaf(wl_.z, xv[r].z, fmaf(wl_.w, xv[r].w, accl[r]))));
            accr[r] = fmaf(wr_.x, xv[r].x, fmaf(wr_.y, xv[r].y,
                      fmaf(wr_.z, xv[r].z, fmaf(wr_.w, xv[r].w, accr[r]))));
        }
        wl_ = wln; wr_ = wrn;
    }
    float bls = bl[j], brs = br[j];
#pragma unroll
    for (int r = 0; r < 8; ++r) {
        int nn = node0 + r0 + r; if (nn > N_NODES - 1) nn = N_NODES - 1;
        size_t n = (size_t)nn;
        xl2[n * HID + j] = accl[r] + bls;
        xr2[n * HID + j] = accr[r] + brs;
    }
}

// ---------- conv1 fused score+softmax+aggregate (wave per node, 8-edge batches) ----------
__global__ __launch_bounds__(256) void k_gat1_fused(
    const int* __restrict__ rs, const int* __restrict__ csr_src,
    const float* __restrict__ xl, const float* __restrict__ xr,
    const float* __restrict__ att, const float* __restrict__ bias,
    float* __restrict__ hout)
{
    int n = (blockIdx.x * 256 + threadIdx.x) >> 6;
    if (n >= N_NODES) return;
    int lane = threadIdx.x & 63;
    int h = lane >> 4;
    const float2* xlp = (const float2*)xl;
    float2 r = *(const float2*)&xr[(size_t)n * D1 + lane * 2];
    float2 a = *(const float2*)&att[h * HID + (lane & 15) * 2];
    float2 l = xlp[(size_t)n * 64 + lane];
    float sc = lrelu_(l.x + r.x) * a.x + lrelu_(l.y + r.y) * a.y;
    sc += __shfl_xor(sc, 1);
    sc += __shfl_xor(sc, 2);
    sc += __shfl_xor(sc, 4);
    sc += __shfl_xor(sc, 8);
    float ex  = __expf(sc);
    float den = ex;
    float2 acc = {ex * l.x, ex * l.y};
    int e0 = rs[n], e1 = rs[n + 1];
    int p = e0;
    for (; p + 8 <= e1; p += 8) {
        int    sA[8];
        float2 ll[8];
        float  sb[8];
#pragma unroll
        for (int i = 0; i < 8; ++i) sA[i] = csr_src[p + i];
#pragma unroll
        for (int i = 0; i < 8; ++i) ll[i] = xlp[(size_t)sA[i] * 64 + lane];
#pragma unroll
        for (int i = 0; i < 8; ++i)
            sb[i] = lrelu_(ll[i].x + r.x) * a.x + lrelu_(ll[i].y + r.y) * a.y;
#pragma unroll
        for (int i = 0; i < 8; ++i) sb[i] += __shfl_xor(sb[i], 1);
#pragma unroll
        for (int i = 0; i < 8; ++i) sb[i] += __shfl_xor(sb[i], 2);
#pragma unroll
        for (int i = 0; i < 8; ++i) sb[i] += __shfl_xor(sb[i], 4);
#pragma unroll
        for (int i = 0; i < 8; ++i) sb[i] += __shfl_xor(sb[i], 8);
#pragma unroll
        for (int i = 0; i < 8; ++i) {
            float exx = __expf(sb[i]);
            den   += exx;
            acc.x += exx * ll[i].x;
            acc.y += exx * ll[i].y;
        }
    }
    for (; p < e1; ++p) {
        int s = csr_src[p];
        float2 ll = xlp[(size_t)s * 64 + lane];
        float  s1 = lrelu_(ll.x + r.x) * a.x + lrelu_(ll.y + r.y) * a.y;
        s1 += __shfl_xor(s1, 1);
        s1 += __shfl_xor(s1, 2);
        s1 += __shfl_xor(s1, 4);
        s1 += __shfl_xor(s1, 8);
        float exx = __expf(s1);
        den   += exx;
        acc.x += exx * ll.x;
        acc.y += exx * ll.y;
    }
    float inv = 1.f / (den + 1e-16f);
    int j = lane * 2;
    float2 o;
    o.x = elu_(acc.x * inv + bias[j]);
    o.y = elu_(acc.y * inv + bias[j + 1]);
    *(float2*)&hout[(size_t)n * D1 + j] = o;   // hout aliases xr: own row only, read-before-write
}

// ---------- conv2 fused score+softmax+aggregate+ELU (half-wave per node) ----------
__global__ __launch_bounds__(256) void k_gat2_fused(
    const int* __restrict__ rs, const int* __restrict__ csr_src,
    const float* __restrict__ xl2, const float* __restrict__ xr2,
    const float* __restrict__ att, const float* __restrict__ bias,
    float* __restrict__ h2)
{
    int n = (blockIdx.x * 256 + threadIdx.x) >> 5;
    if (n >= N_NODES) return;
    int lane = threadIdx.x & 31;
    float r = xr2[n * HID + lane];
    float a = att[lane];
    float l  = xl2[n * HID + lane];
    float sc = lrelu_(l + r) * a;
    sc += __shfl_xor(sc, 1);
    sc += __shfl_xor(sc, 2);
    sc += __shfl_xor(sc, 4);
    sc += __shfl_xor(sc, 8);
    sc += __shfl_xor(sc, 16);
    float ex  = __expf(sc);
    float den = ex;
    float acc = ex * l;
    int e0 = rs[n], e1 = rs[n + 1];
    int p = e0;
    for (; p + 8 <= e1; p += 8) {
        int   sA[8];
        float ll[8];
        float sb[8];
#pragma unroll
        for (int i = 0; i < 8; ++i) sA[i] = csr_src[p + i];
#pragma unroll
        for (int i = 0; i < 8; ++i) ll[i] = xl2[sA[i] * HID + lane];
#pragma unroll
        for (int i = 0; i < 8; ++i) sb[i] = lrelu_(ll[i] + r) * a;
#pragma unroll
        for (int i = 0; i < 8; ++i) sb[i] += __shfl_xor(sb[i], 1);
#pragma unroll
        for (int i = 0; i < 8; ++i) sb[i] += __shfl_xor(sb[i], 2);
#pragma unroll
        for (int i = 0; i < 8; ++i) sb[i] += __shfl_xor(sb[i], 4);
#pragma unroll
        for (int i = 0; i < 8; ++i) sb[i] += __shfl_xor(sb[i], 8);
#pragma unroll
        for (int i = 0; i < 8; ++i) sb[i] += __shfl_xor(sb[i], 16);
#pragma unroll
        for (int i = 0; i < 8; ++i) {
            float exx = __expf(sb[i]);
            den += exx;
            acc += exx * ll[i];
        }
    }
    for (; p < e1; ++p) {
        int s = csr_src[p];
        float ll = xl2[s * HID + lane];
        float s1 = lrelu_(ll + r) * a;
        s1 += __shfl_xor(s1, 1);
        s1 += __shfl_xor(s1, 2);
        s1 += __shfl_xor(s1, 4);
        s1 += __shfl_xor(s1, 8);
        s1 += __shfl_xor(s1, 16);
        float exx = __expf(s1);
        den += exx;
        acc += exx * ll;
    }
    h2[n * HID + lane] = elu_(acc / (den + 1e-16f) + bias[lane]);
}

// ---------- per-graph mean pool + both heads ----------
__global__ __launch_bounds__(256) void k_pool_heads(
    const float* __restrict__ h2, const int* __restrict__ gstart,
    const float* __restrict__ wc, const float* __restrict__ bc,
    const float* __restrict__ wp, const float* __restrict__ bp,
    float* __restrict__ out)
{
    int g  = blockIdx.x;
    int n0 = gstart[g], n1 = gstart[g + 1];
    int c    = threadIdx.x & 31;
    int slot = threadIdx.x >> 5;   // 0..7
    float s = 0.f;
    for (int n = n0 + slot; n < n1; n += 8)
        s += h2[n * HID + c];
    __shared__ float red[8][HID];
    red[slot][c] = s;
    __syncthreads();
    if (slot == 0) {
        float tot = 0.f;
#pragma unroll
        for (int i = 0; i < 8; ++i) tot += red[i][c];
        float cntf = fmaxf((float)(n1 - n0), 1.f);
        float p = tot / cntf;
        float sc = p * wc[c];
        float sp = p * wp[c];
        sc += __shfl_xor(sc, 1);  sp += __shfl_xor(sp, 1);
        sc += __shfl_xor(sc, 2);  sp += __shfl_xor(sp, 2);
        sc += __shfl_xor(sc, 4);  sp += __shfl_xor(sp, 4);
        sc += __shfl_xor(sc, 8);  sp += __shfl_xor(sp, 8);
        sc += __shfl_xor(sc, 16); sp += __shfl_xor(sp, 16);
        if (c == 0) {
            out[g]          = sc + bc[0];
            out[NGRAPH + g] = sp + bp[0];
        }
    }
}

extern "C" void kernel_launch(void* const* d_in, const int* in_sizes, int n_in,
                              void* d_out, int out_size, void* d_ws, size_t ws_size,
                              hipStream_t stream)
{
    const float* x     = (const float*)d_in[0];
    const int*   ei    = (const int*)d_in[1];
    const int*   batch = (const int*)d_in[2];
    const float* w1l   = (const float*)d_in[3];
    const float* b1l   = (const float*)d_in[4];
    const float* w1r   = (const float*)d_in[5];
    const float* b1r   = (const float*)d_in[6];
    const float* att1  = (const float*)d_in[7];
    const float* bias1 = (const float*)d_in[8];
    const float* w2l   = (const float*)d_in[9];
    const float* b2l   = (const float*)d_in[10];
    const float* w2r   = (const float*)d_in[11];
    const float* b2r   = (const float*)d_in[12];
    const float* att2  = (const float*)d_in[13];
    const float* bias2 = (const float*)d_in[14];
    const float* wc    = (const float*)d_in[15];
    const float* bc    = (const float*)d_in[16];
    const float* wp    = (const float*)d_in[17];
    const float* bp    = (const float*)d_in[18];
    float* out = (float*)d_out;

    float* ws   = (float*)d_ws;
    // conv1 phase
    float* xl1  = ws;                 // 6,400,000 floats   [0 .. 6.4M)
    float* xr1  = ws + 6400000;       // 6,400,000          [6.4M .. 12.8M)
    float* hbuf = ws + 6400000;       // ALIASES xr1 (safe: per-wave read-own-row-then-write)
    // conv2 phase (xl1 region dead after k_gat1_fused)
    float* xl2  = ws;                 // 1,600,000
    float* xr2  = ws + 1600000;       // 1,600,000
    float* h2   = ws + 3200000;       // 1,600,000
    // int region (after 12.8M floats)
    int* ibase   = (int*)(ws + 12800000);
    int* deg     = ibase;              //  50,000
    int* rs      = ibase + 50000;      //  50,001
    int* cur     = ibase + 100001;     //  50,000
    int* csr_src = ibase + 150001;     // 800,000
    int* gstart  = ibase + 950001;     //      65
    int* btot    = ibase + 950101;     //      49
    int* boff    = ibase + 950151;     //      49
    // re-laid-out weights
    float* wtg1 = ws + 13800000;       // 32,768
    float* wtg2 = ws + 13840000;       //  8,192

    // ---- one-time weight re-layout + CSR build + graph boundaries ----
    k_wtrans1<<<128, 256, 0, stream>>>(w1l, w1r, wtg1);
    k_wtrans2<<<32, 256, 0, stream>>>(w2l, w2r, wtg2);
    hipMemsetAsync(deg, 0, N_NODES * sizeof(int), stream);
    hipMemsetAsync(cur, 0, N_NODES * sizeof(int), stream);
    k_hist<<<(N_EDGES + 255) / 256, 256, 0, stream>>>(ei, deg);
    k_scan_local<<<SCAN_NB, 1024, 0, stream>>>(deg, rs, btot);
    k_scan_btot<<<1, 64, 0, stream>>>(btot, boff);
    k_scan_add<<<SCAN_NB, 1024, 0, stream>>>(rs, boff);
    k_scatter<<<(N_EDGES + 255) / 256, 256, 0, stream>>>(ei, rs, cur, csr_src);
    k_gbound<<<(N_NODES + 1 + 255) / 256, 256, 0, stream>>>(batch, gstart);

    // ---- conv1 ----
    k_transform1<<<(N_NODES + 31) / 32, 256, 0, stream>>>(x, wtg1, b1l, b1r, xl1, xr1);
    k_gat1_fused<<<(N_NODES * 64 + 255) / 256, 256, 0, stream>>>(rs, csr_src, xl1, xr1, att1, bias1, hbuf);

    // ---- conv2 ----
    k_transform2<<<(N_NODES + 63) / 64, 256, 0, stream>>>(hbuf, wtg2, b2l, b2r, xl2, xr2);
    k_gat2_fused<<<(N_NODES * 32 + 255) / 256, 256, 0, stream>>>(rs, csr_src, xl2, xr2, att2, bias2, h2);

    // ---- pool + heads ----
    k_pool_heads<<<NGRAPH, 256, 0, stream>>>(h2, gstart, wc, bc, wp, bp, out);
}

// Round 2
// 298.488 us; speedup vs baseline: 1.0690x; 1.0644x over previous
//
#include <hip/hip_runtime.h>

#define N_NODES 50000
#define N_EDGES 800000
#define FEATS   128
#define HID     32
#define HEADS   4
#define D1      128      // HEADS*HID
#define NGRAPH  64
#define SCAN_NB ((N_NODES + 1023) / 1024)   // 49

__device__ __forceinline__ float lrelu_(float v) { return v > 0.f ? v : 0.2f * v; }
__device__ __forceinline__ float elu_(float v)   { return v > 0.f ? v : __expf(v) - 1.f; }

// ---------- CSR build ----------
__global__ __launch_bounds__(256) void k_hist(const int* __restrict__ ei, int* __restrict__ deg)
{
    int e = blockIdx.x * 256 + threadIdx.x;
    if (e < N_EDGES) atomicAdd(&deg[ei[N_EDGES + e]], 1);
}

// phase A: per-block exclusive scan + block totals
__global__ __launch_bounds__(1024) void k_scan_local(
    const int* __restrict__ deg, int* __restrict__ rs, int* __restrict__ btot)
{
    __shared__ int sm[1024];
    int idx = blockIdx.x * 1024 + threadIdx.x;
    int v = (idx < N_NODES) ? deg[idx] : 0;
    sm[threadIdx.x] = v;
    __syncthreads();
    for (int off = 1; off < 1024; off <<= 1) {
        int t = (threadIdx.x >= off) ? sm[threadIdx.x - off] : 0;
        __syncthreads();
        sm[threadIdx.x] += t;
        __syncthreads();
    }
    if (idx < N_NODES) rs[idx] = sm[threadIdx.x] - v;   // exclusive
    if (threadIdx.x == 1023) btot[blockIdx.x] = sm[1023];
}

// phase B: single-wave shuffle scan of the 49 block totals -> exclusive offsets
__global__ __launch_bounds__(64) void k_scan_btot(
    const int* __restrict__ btot, int* __restrict__ boff)
{
    int t = threadIdx.x;
    int own = (t < SCAN_NB) ? btot[t] : 0;
    int v = own;
    for (int off = 1; off < 64; off <<= 1) {
        int u = __shfl_up(v, off);
        if (t >= off) v += u;
    }
    if (t < SCAN_NB) boff[t] = v - own;   // exclusive
}

// phase C: add block offsets; rs[N_NODES] = N_EDGES
__global__ __launch_bounds__(1024) void k_scan_add(
    int* __restrict__ rs, const int* __restrict__ boff)
{
    int idx = blockIdx.x * 1024 + threadIdx.x;
    if (idx < N_NODES) rs[idx] += boff[blockIdx.x];
    if (idx == N_NODES) rs[N_NODES] = N_EDGES;
}

__global__ __launch_bounds__(256) void k_scatter(const int* __restrict__ ei,
                                                const int* __restrict__ rs,
                                                int* __restrict__ cur,
                                                int* __restrict__ csr_src)
{
    int e = blockIdx.x * 256 + threadIdx.x;
    if (e >= N_EDGES) return;
    int d = ei[N_EDGES + e];
    int p = rs[d] + atomicAdd(&cur[d], 1);
    csr_src[p] = ei[e];
}

// graph boundaries from sorted batch
__global__ __launch_bounds__(256) void k_gbound(const int* __restrict__ batch, int* __restrict__ gstart)
{
    int i = blockIdx.x * 256 + threadIdx.x;
    if (i > N_NODES) return;
    int b    = (i < N_NODES) ? batch[i] : NGRAPH;
    int prev = (i == 0) ? -1 : batch[i - 1];
    for (int g = prev + 1; g <= b; ++g) gstart[g] = i;
}

// ---------- weight re-layout (one-time, tiny) ----------
__global__ __launch_bounds__(256) void k_wtrans1(
    const float* __restrict__ wl, const float* __restrict__ wr, float* __restrict__ wtg)
{
    int idx = blockIdx.x * 256 + threadIdx.x;   // 32768
    if (idx >= 32 * 256 * 4) return;
    int kk = idx & 3, j = (idx >> 2) & 255, k4 = idx >> 10;
    int k = k4 * 4 + kk;
    wtg[idx] = (j < 128) ? wl[j * FEATS + k] : wr[(j - 128) * FEATS + k];
}

__global__ __launch_bounds__(256) void k_wtrans2(
    const float* __restrict__ wl, const float* __restrict__ wr, float* __restrict__ wtg)
{
    int idx = blockIdx.x * 256 + threadIdx.x;   // 8192
    if (idx >= 32 * 64 * 4) return;
    int kk = idx & 3, j = (idx >> 2) & 63, k4 = idx >> 8;
    int k = k4 * 4 + kk;
    wtg[idx] = (j < 32) ? wl[j * D1 + k] : wr[(j - 32) * D1 + k];
}

// ---------- conv1 transform: 32 nodes/block, 8 nodes/thread, prefetched weights ----------
__global__ __launch_bounds__(256, 2) void k_transform1(
    const float* __restrict__ x, const float* __restrict__ wtg,
    const float* __restrict__ bl, const float* __restrict__ br,
    float* __restrict__ xl, float* __restrict__ xr)
{
    __shared__ float4 xs[32][32];   // [node][k4] : 16 KB
    int node0 = blockIdx.x * 32;
    for (int i = threadIdx.x; i < 1024; i += 256) {
        int r = i >> 5, k4 = i & 31;
        int n = node0 + r; if (n > N_NODES - 1) n = N_NODES - 1;   // tail clamp (pure fn -> benign dup)
        xs[r][k4] = *(const float4*)&x[(size_t)n * FEATS + k4 * 4];
    }
    __syncthreads();
    int jg = threadIdx.x & 63;
    int r0 = (threadIdx.x >> 6) * 8;
    const float4* wp = (const float4*)wtg;
    float acc[8][4];
#pragma unroll
    for (int r = 0; r < 8; ++r)
#pragma unroll
        for (int c = 0; c < 4; ++c) acc[r][c] = 0.f;

    float4 w[4];
#pragma unroll
    for (int c = 0; c < 4; ++c) w[c] = wp[jg + 64 * c];

#pragma unroll 2
    for (int k4 = 0; k4 < 32; ++k4) {
        int k4n = (k4 < 31) ? k4 + 1 : 31;
        float4 wn[4];
#pragma unroll
        for (int c = 0; c < 4; ++c) wn[c] = wp[k4n * 256 + jg + 64 * c];
        float4 xv[8];
#pragma unroll
        for (int r = 0; r < 8; ++r) xv[r] = xs[r0 + r][k4];
#pragma unroll
        for (int c = 0; c < 4; ++c)
#pragma unroll
            for (int r = 0; r < 8; ++r)
                acc[r][c] = fmaf(w[c].x, xv[r].x, fmaf(w[c].y, xv[r].y,
                            fmaf(w[c].z, xv[r].z, fmaf(w[c].w, xv[r].w, acc[r][c]))));
#pragma unroll
        for (int c = 0; c < 4; ++c) w[c] = wn[c];
    }
    float bl0 = bl[jg], bl1 = bl[jg + 64];
    float br0 = br[jg], br1 = br[jg + 64];
#pragma unroll
    for (int r = 0; r < 8; ++r) {
        int nn = node0 + r0 + r; if (nn > N_NODES - 1) nn = N_NODES - 1;
        size_t n = (size_t)nn;
        xl[n * D1 + jg]      = acc[r][0] + bl0;
        xl[n * D1 + jg + 64] = acc[r][1] + bl1;
        xr[n * D1 + jg]      = acc[r][2] + br0;
        xr[n * D1 + jg + 64] = acc[r][3] + br1;
    }
}

// ---------- conv2 transform: 64 nodes/block, 8 nodes/thread, 2 cols/thread ----------
__global__ __launch_bounds__(256, 2) void k_transform2(
    const float* __restrict__ hin, const float* __restrict__ wtg,
    const float* __restrict__ bl, const float* __restrict__ br,
    float* __restrict__ xl2, float* __restrict__ xr2)
{
    __shared__ float4 xs[64][32];   // 32 KB
    int node0 = blockIdx.x * 64;
    for (int i = threadIdx.x; i < 2048; i += 256) {
        int r = i >> 5, k4 = i & 31;
        int n = node0 + r; if (n > N_NODES - 1) n = N_NODES - 1;
        xs[r][k4] = *(const float4*)&hin[(size_t)n * D1 + k4 * 4];
    }
    __syncthreads();
    int j  = threadIdx.x & 31;        // output col (serves both L and R side)
    int r0 = (threadIdx.x >> 5) * 8;  // 8 groups x 8 nodes = 64
    const float4* wp = (const float4*)wtg;
    float accl[8], accr[8];
#pragma unroll
    for (int r = 0; r < 8; ++r) { accl[r] = 0.f; accr[r] = 0.f; }

    float4 wl_ = wp[j], wr_ = wp[j + 32];

#pragma unroll 2
    for (int k4 = 0; k4 < 32; ++k4) {
        int k4n = (k4 < 31) ? k4 + 1 : 31;
        float4 wln = wp[k4n * 64 + j];
        float4 wrn = wp[k4n * 64 + j + 32];
        float4 xv[8];
#pragma unroll
        for (int r = 0; r < 8; ++r) xv[r] = xs[r0 + r][k4];
#pragma unroll
        for (int r = 0; r < 8; ++r) {
            accl[r] = fmaf(wl_.x, xv[r].x, fmaf(wl_.y, xv[r].y,
                      fmaf(wl_.z, xv[r].z, fmaf(wl_.w, xv[r].w, accl[r]))));
            accr[r] = fmaf(wr_.x, xv[r].x, fmaf(wr_.y, xv[r].y,
                      fmaf(wr_.z, xv[r].z, fmaf(wr_.w, xv[r].w, accr[r]))));
        }
        wl_ = wln; wr_ = wrn;
    }
    float bls = bl[j], brs = br[j];
#pragma unroll
    for (int r = 0; r < 8; ++r) {
        int nn = node0 + r0 + r; if (nn > N_NODES - 1) nn = N_NODES - 1;
        size_t n = (size_t)nn;
        xl2[n * HID + j] = accl[r] + bls;
        xr2[n * HID + j] = accr[r] + brs;
    }
}

// ---------- conv1 fused: wave per node, 2 edges/wave, float4 (16B) gathers ----------
// lane layout: d0 = lane&31 -> float4 slot of the 128-float row; half = lane>>5 -> edge of pair.
// head of slot d0 is d0>>3; score reduce = shfl_xor 1,2,4 over the 8-lane head group.
// halves combined once at the end via shfl_xor(...,32).
__global__ __launch_bounds__(256) void k_gat1_fused(
    const int* __restrict__ rs, const int* __restrict__ csr_src,
    const float* __restrict__ xl, const float* __restrict__ xr,
    const float* __restrict__ att, const float* __restrict__ bias,
    float* __restrict__ hout)
{
    int n = (blockIdx.x * 256 + threadIdx.x) >> 6;
    if (n >= N_NODES) return;
    int lane = threadIdx.x & 63;
    int d0   = lane & 31;
    int half = lane >> 5;
    const float4* xlp = (const float4*)xl;
    float4 r = ((const float4*)xr)[(size_t)n * 32 + d0];
    float4 a = ((const float4*)att)[d0];   // att[h*32 + c] -> float4 index == d0
    // self edge (counted on half 0 only)
    float4 l = xlp[(size_t)n * 32 + d0];
    float sc = lrelu_(l.x + r.x) * a.x + lrelu_(l.y + r.y) * a.y
             + lrelu_(l.z + r.z) * a.z + lrelu_(l.w + r.w) * a.w;
    sc += __shfl_xor(sc, 1);
    sc += __shfl_xor(sc, 2);
    sc += __shfl_xor(sc, 4);
    float ex  = (half == 0) ? __expf(sc) : 0.f;
    float den = ex;
    float4 acc = { ex * l.x, ex * l.y, ex * l.z, ex * l.w };
    int e0 = rs[n], e1 = rs[n + 1];
    int p = e0;
    for (; p + 8 <= e1; p += 8) {        // 4 pairs = 8 edges, all valid
        int    sA[4];
        float4 ll[4];
        float  sb[4];
#pragma unroll
        for (int i = 0; i < 4; ++i) sA[i] = csr_src[p + 2 * i + half];
#pragma unroll
        for (int i = 0; i < 4; ++i) ll[i] = xlp[(size_t)sA[i] * 32 + d0];
#pragma unroll
        for (int i = 0; i < 4; ++i)
            sb[i] = lrelu_(ll[i].x + r.x) * a.x + lrelu_(ll[i].y + r.y) * a.y
                  + lrelu_(ll[i].z + r.z) * a.z + lrelu_(ll[i].w + r.w) * a.w;
#pragma unroll
        for (int i = 0; i < 4; ++i) sb[i] += __shfl_xor(sb[i], 1);
#pragma unroll
        for (int i = 0; i < 4; ++i) sb[i] += __shfl_xor(sb[i], 2);
#pragma unroll
        for (int i = 0; i < 4; ++i) sb[i] += __shfl_xor(sb[i], 4);
#pragma unroll
        for (int i = 0; i < 4; ++i) {
            float exx = __expf(sb[i]);
            den   += exx;
            acc.x += exx * ll[i].x;
            acc.y += exx * ll[i].y;
            acc.z += exx * ll[i].z;
            acc.w += exx * ll[i].w;
        }
    }
    for (; p < e1; p += 2) {             // tail pairs, half-validity masked
        int  idx = p + half;
        bool v   = idx < e1;
        int  s   = csr_src[v ? idx : e1 - 1];
        float4 ll = xlp[(size_t)s * 32 + d0];
        float  s1 = lrelu_(ll.x + r.x) * a.x + lrelu_(ll.y + r.y) * a.y
                  + lrelu_(ll.z + r.z) * a.z + lrelu_(ll.w + r.w) * a.w;
        s1 += __shfl_xor(s1, 1);
        s1 += __shfl_xor(s1, 2);
        s1 += __shfl_xor(s1, 4);
        float exx = v ? __expf(s1) : 0.f;
        den   += exx;
        acc.x += exx * ll.x;
        acc.y += exx * ll.y;
        acc.z += exx * ll.z;
        acc.w += exx * ll.w;
    }
    // combine halves
    den   += __shfl_xor(den, 32);
    acc.x += __shfl_xor(acc.x, 32);
    acc.y += __shfl_xor(acc.y, 32);
    acc.z += __shfl_xor(acc.z, 32);
    acc.w += __shfl_xor(acc.w, 32);
    if (half == 0) {
        float inv = 1.f / (den + 1e-16f);
        float4 b = ((const float4*)bias)[d0];
        float4 o;
        o.x = elu_(acc.x * inv + b.x);
        o.y = elu_(acc.y * inv + b.y);
        o.z = elu_(acc.z * inv + b.z);
        o.w = elu_(acc.w * inv + b.w);
        ((float4*)hout)[(size_t)n * 32 + d0] = o;   // hout aliases xr: own row only, read-before-write
    }
}

// ---------- conv2 fused: half-wave per node, 4 edges in flight, float4 gathers ----------
// lane&31 split: d0 = lane&7 -> float4 slot of the 32-float row; sub = (lane&31)>>3 -> edge of quad.
// score reduce = shfl_xor 1,2,4 (8-lane group); subs combined via shfl_xor 8,16 (stays in half).
__global__ __launch_bounds__(256) void k_gat2_fused(
    const int* __restrict__ rs, const int* __restrict__ csr_src,
    const float* __restrict__ xl2, const float* __restrict__ xr2,
    const float* __restrict__ att, const float* __restrict__ bias,
    float* __restrict__ h2)
{
    int n = (blockIdx.x * 256 + threadIdx.x) >> 5;
    if (n >= N_NODES) return;
    int lane = threadIdx.x & 31;
    int d0   = lane & 7;
    int sub  = lane >> 3;
    const float4* xlp = (const float4*)xl2;
    float4 r = ((const float4*)xr2)[(size_t)n * 8 + d0];
    float4 a = ((const float4*)att)[d0];
    // self edge (sub 0 only)
    float4 l = xlp[(size_t)n * 8 + d0];
    float sc = lrelu_(l.x + r.x) * a.x + lrelu_(l.y + r.y) * a.y
             + lrelu_(l.z + r.z) * a.z + lrelu_(l.w + r.w) * a.w;
    sc += __shfl_xor(sc, 1);
    sc += __shfl_xor(sc, 2);
    sc += __shfl_xor(sc, 4);
    float ex  = (sub == 0) ? __expf(sc) : 0.f;
    float den = ex;
    float4 acc = { ex * l.x, ex * l.y, ex * l.z, ex * l.w };
    int e0 = rs[n], e1 = rs[n + 1];
    int p = e0;
    for (; p + 16 <= e1; p += 16) {      // 4 quads = 16 edges, all valid
        int    sA[4];
        float4 ll[4];
        float  sb[4];
#pragma unroll
        for (int i = 0; i < 4; ++i) sA[i] = csr_src[p + 4 * i + sub];
#pragma unroll
        for (int i = 0; i < 4; ++i) ll[i] = xlp[(size_t)sA[i] * 8 + d0];
#pragma unroll
        for (int i = 0; i < 4; ++i)
            sb[i] = lrelu_(ll[i].x + r.x) * a.x + lrelu_(ll[i].y + r.y) * a.y
                  + lrelu_(ll[i].z + r.z) * a.z + lrelu_(ll[i].w + r.w) * a.w;
#pragma unroll
        for (int i = 0; i < 4; ++i) sb[i] += __shfl_xor(sb[i], 1);
#pragma unroll
        for (int i = 0; i < 4; ++i) sb[i] += __shfl_xor(sb[i], 2);
#pragma unroll
        for (int i = 0; i < 4; ++i) sb[i] += __shfl_xor(sb[i], 4);
#pragma unroll
        for (int i = 0; i < 4; ++i) {
            float exx = __expf(sb[i]);
            den   += exx;
            acc.x += exx * ll[i].x;
            acc.y += exx * ll[i].y;
            acc.z += exx * ll[i].z;
            acc.w += exx * ll[i].w;
        }
    }
    for (; p < e1; p += 4) {             // tail quads, validity masked
        int  idx = p + sub;
        bool v   = idx < e1;
        int  s   = csr_src[v ? idx : e1 - 1];
        float4 ll = xlp[(size_t)s * 8 + d0];
        float  s1 = lrelu_(ll.x + r.x) * a.x + lrelu_(ll.y + r.y) * a.y
                  + lrelu_(ll.z + r.z) * a.z + lrelu_(ll.w + r.w) * a.w;
        s1 += __shfl_xor(s1, 1);
        s1 += __shfl_xor(s1, 2);
        s1 += __shfl_xor(s1, 4);
        float exx = v ? __expf(s1) : 0.f;
        den   += exx;
        acc.x += exx * ll.x;
        acc.y += exx * ll.y;
        acc.z += exx * ll.z;
        acc.w += exx * ll.w;
    }
    // combine the 4 subgroups (masks stay inside the 32-lane half)
    den   += __shfl_xor(den, 8);
    den   += __shfl_xor(den, 16);
    acc.x += __shfl_xor(acc.x, 8);  acc.x += __shfl_xor(acc.x, 16);
    acc.y += __shfl_xor(acc.y, 8);  acc.y += __shfl_xor(acc.y, 16);
    acc.z += __shfl_xor(acc.z, 8);  acc.z += __shfl_xor(acc.z, 16);
    acc.w += __shfl_xor(acc.w, 8);  acc.w += __shfl_xor(acc.w, 16);
    if (sub == 0) {
        float inv = 1.f / (den + 1e-16f);
        float4 b = ((const float4*)bias)[d0];
        float4 o;
        o.x = elu_(acc.x * inv + b.x);
        o.y = elu_(acc.y * inv + b.y);
        o.z = elu_(acc.z * inv + b.z);
        o.w = elu_(acc.w * inv + b.w);
        ((float4*)h2)[(size_t)n * 8 + d0] = o;
    }
}

// ---------- per-graph mean pool + both heads ----------
__global__ __launch_bounds__(256) void k_pool_heads(
    const float* __restrict__ h2, const int* __restrict__ gstart,
    const float* __restrict__ wc, const float* __restrict__ bc,
    const float* __restrict__ wp, const float* __restrict__ bp,
    float* __restrict__ out)
{
    int g  = blockIdx.x;
    int n0 = gstart[g], n1 = gstart[g + 1];
    int c    = threadIdx.x & 31;
    int slot = threadIdx.x >> 5;   // 0..7
    float s = 0.f;
    for (int n = n0 + slot; n < n1; n += 8)
        s += h2[n * HID + c];
    __shared__ float red[8][HID];
    red[slot][c] = s;
    __syncthreads();
    if (slot == 0) {
        float tot = 0.f;
#pragma unroll
        for (int i = 0; i < 8; ++i) tot += red[i][c];
        float cntf = fmaxf((float)(n1 - n0), 1.f);
        float p = tot / cntf;
        float sc = p * wc[c];
        float sp = p * wp[c];
        sc += __shfl_xor(sc, 1);  sp += __shfl_xor(sp, 1);
        sc += __shfl_xor(sc, 2);  sp += __shfl_xor(sp, 2);
        sc += __shfl_xor(sc, 4);  sp += __shfl_xor(sp, 4);
        sc += __shfl_xor(sc, 8);  sp += __shfl_xor(sp, 8);
        sc += __shfl_xor(sc, 16); sp += __shfl_xor(sp, 16);
        if (c == 0) {
            out[g]          = sc + bc[0];
            out[NGRAPH + g] = sp + bp[0];
        }
    }
}

extern "C" void kernel_launch(void* const* d_in, const int* in_sizes, int n_in,
                              void* d_out, int out_size, void* d_ws, size_t ws_size,
                              hipStream_t stream)
{
    const float* x     = (const float*)d_in[0];
    const int*   ei    = (const int*)d_in[1];
    const int*   batch = (const int*)d_in[2];
    const float* w1l   = (const float*)d_in[3];
    const float* b1l   = (const float*)d_in[4];
    const float* w1r   = (const float*)d_in[5];
    const float* b1r   = (const float*)d_in[6];
    const float* att1  = (const float*)d_in[7];
    const float* bias1 = (const float*)d_in[8];
    const float* w2l   = (const float*)d_in[9];
    const float* b2l   = (const float*)d_in[10];
    const float* w2r   = (const float*)d_in[11];
    const float* b2r   = (const float*)d_in[12];
    const float* att2  = (const float*)d_in[13];
    const float* bias2 = (const float*)d_in[14];
    const float* wc    = (const float*)d_in[15];
    const float* bc    = (const float*)d_in[16];
    const float* wp    = (const float*)d_in[17];
    const float* bp    = (const float*)d_in[18];
    float* out = (float*)d_out;

    float* ws   = (float*)d_ws;
    // conv1 phase
    float* xl1  = ws;                 // 6,400,000 floats   [0 .. 6.4M)
    float* xr1  = ws + 6400000;       // 6,400,000          [6.4M .. 12.8M)
    float* hbuf = ws + 6400000;       // ALIASES xr1 (safe: per-wave read-own-row-then-write)
    // conv2 phase (xl1 region dead after k_gat1_fused)
    float* xl2  = ws;                 // 1,600,000
    float* xr2  = ws + 1600000;       // 1,600,000
    float* h2   = ws + 3200000;       // 1,600,000
    // int region (after 12.8M floats)
    int* ibase   = (int*)(ws + 12800000);
    int* deg     = ibase;              //  50,000
    int* rs      = ibase + 50000;      //  50,001
    int* cur     = ibase + 100001;     //  50,000
    int* csr_src = ibase + 150001;     // 800,000
    int* gstart  = ibase + 950001;     //      65
    int* btot    = ibase + 950101;     //      49
    int* boff    = ibase + 950151;     //      49
    // re-laid-out weights
    float* wtg1 = ws + 13800000;       // 32,768
    float* wtg2 = ws + 13840000;       //  8,192

    // ---- one-time weight re-layout + CSR build + graph boundaries ----
    k_wtrans1<<<128, 256, 0, stream>>>(w1l, w1r, wtg1);
    k_wtrans2<<<32, 256, 0, stream>>>(w2l, w2r, wtg2);
    hipMemsetAsync(deg, 0, N_NODES * sizeof(int), stream);
    hipMemsetAsync(cur, 0, N_NODES * sizeof(int), stream);
    k_hist<<<(N_EDGES + 255) / 256, 256, 0, stream>>>(ei, deg);
    k_scan_local<<<SCAN_NB, 1024, 0, stream>>>(deg, rs, btot);
    k_scan_btot<<<1, 64, 0, stream>>>(btot, boff);
    k_scan_add<<<SCAN_NB, 1024, 0, stream>>>(rs, boff);
    k_scatter<<<(N_EDGES + 255) / 256, 256, 0, stream>>>(ei, rs, cur, csr_src);
    k_gbound<<<(N_NODES + 1 + 255) / 256, 256, 0, stream>>>(batch, gstart);

    // ---- conv1 ----
    k_transform1<<<(N_NODES + 31) / 32, 256, 0, stream>>>(x, wtg1, b1l, b1r, xl1, xr1);
    k_gat1_fused<<<(N_NODES * 64 + 255) / 256, 256, 0, stream>>>(rs, csr_src, xl1, xr1, att1, bias1, hbuf);

    // ---- conv2 ----
    k_transform2<<<(N_NODES + 63) / 64, 256, 0, stream>>>(hbuf, wtg2, b2l, b2r, xl2, xr2);
    k_gat2_fused<<<(N_NODES * 32 + 255) / 256, 256, 0, stream>>>(rs, csr_src, xl2, xr2, att2, bias2, h2);

    // ---- pool + heads ----
    k_pool_heads<<<NGRAPH, 256, 0, stream>>>(h2, gstart, wc, bc, wp, bp, out);
}